// Round 2
// baseline (463.514 us; speedup 1.0000x reference)
//
#include <hip/hip_runtime.h>
#include <hip/hip_bf16.h>

typedef __attribute__((ext_vector_type(4))) float f32x4;
typedef __attribute__((ext_vector_type(8))) short s16x8;

#define NB_ 4
#define N_ 4096
#define FI_ 256
#define FO_ 128
#define NSTEP 128   // 4096 / 32
#define NROWS 16384 // NB_ * N_

// pack two f32 -> one u32 of 2 bf16 (RNE), first arg in low half
__device__ inline unsigned pkbf(float a, float b) {
    __hip_bfloat162 t = __float22bfloat162_rn(make_float2(a, b));
    unsigned r; __builtin_memcpy(&r, &t, 4); return r;
}

// ---------------- K0: pack W into bf16 hi/lo (done once per launch) ------
__global__ __launch_bounds__(256) void k0_packw(
    const float* __restrict__ Ww, __hip_bfloat16* __restrict__ whi,
    __hip_bfloat16* __restrict__ wlo)
{
    int idx = blockIdx.x * 256 + threadIdx.x;           // 32768 elems
    float v = Ww[idx];
    __hip_bfloat16 hi = __float2bfloat16(v);
    whi[idx] = hi;
    wlo[idx] = __float2bfloat16(v - __bfloat162float(hi));
}

// ---------------- K1: Wh = h @ W^T + Wb  (split-bf16, 3 MFMA, err ~1e-5) -
// grid 1024: block = 16 rows; wave w handles cols [w*32, w*32+32)
__global__ __launch_bounds__(256) void k1_wh(
    const float* __restrict__ h, const __hip_bfloat16* __restrict__ whi,
    const __hip_bfloat16* __restrict__ wlo, const float* __restrict__ Wb,
    float* __restrict__ Wh, __hip_bfloat16* __restrict__ WhT)
{
    const int tid = threadIdx.x;
    const int w = tid >> 6, l = tid & 63;
    const int lr = l & 15, g = l >> 4;
    const int r0 = blockIdx.x * 16;
    const float* hp = h + (size_t)(r0 + lr) * FI_ + g * 8;

    f32x4 acc[2] = {(f32x4)0.f, (f32x4)0.f};

    #pragma unroll
    for (int kt = 0; kt < 8; ++kt) {
        f32x4 x0 = *(const f32x4*)(hp + kt * 32);
        f32x4 x1 = *(const f32x4*)(hp + kt * 32 + 4);
        float xx[8];
        #pragma unroll
        for (int t = 0; t < 4; ++t) { xx[t] = x0[t]; xx[t + 4] = x1[t]; }
        union { s16x8 v; unsigned u[4]; } ahi, alo;
        #pragma unroll
        for (int t = 0; t < 4; ++t) {
            float a0 = xx[2 * t], a1 = xx[2 * t + 1];
            unsigned uh = pkbf(a0, a1);
            ahi.u[t] = uh;
            float h0f = __uint_as_float(uh << 16);
            float h1f = __uint_as_float(uh & 0xffff0000u);
            alo.u[t] = pkbf(a0 - h0f, a1 - h1f);
        }
        #pragma unroll
        for (int c = 0; c < 2; ++c) {
            const int o = w * 32 + c * 16 + lr;
            s16x8 bh = *(const s16x8*)(whi + (size_t)o * FI_ + kt * 32 + g * 8);
            s16x8 bl = *(const s16x8*)(wlo + (size_t)o * FI_ + kt * 32 + g * 8);
            acc[c] = __builtin_amdgcn_mfma_f32_16x16x32_bf16(ahi.v, bh, acc[c], 0, 0, 0);
            acc[c] = __builtin_amdgcn_mfma_f32_16x16x32_bf16(alo.v, bh, acc[c], 0, 0, 0);
            acc[c] = __builtin_amdgcn_mfma_f32_16x16x32_bf16(ahi.v, bl, acc[c], 0, 0, 0);
        }
    }

    // C/D layout: col=lane&15, row=(lane>>4)*4+reg  [m89]
    #pragma unroll
    for (int c = 0; c < 2; ++c) {
        int col = w * 32 + c * 16 + lr;
        float wb = Wb[col];
        #pragma unroll
        for (int kk = 0; kk < 4; ++kk) {
            int grow = r0 + g * 4 + kk;
            float val = acc[c][kk] + wb;
            Wh[(size_t)grow * FO_ + col] = val;
            int bb = grow >> 12, nn = grow & 4095;
            WhT[((size_t)bb * FO_ + col) * N_ + nn] = __float2bfloat16(val);
        }
    }
}

// ---------------- K2: src/dst + E1/E2 tables + per-batch max(dst+a_b) ----
__global__ __launch_bounds__(256) void k2_vec(
    const float* __restrict__ Wh, const float* __restrict__ aw,
    const float* __restrict__ ab, float* __restrict__ srcv,
    float* __restrict__ dstbv, float* __restrict__ e1v,
    float* __restrict__ e2v, unsigned* __restrict__ maxenc)
{
    const int w = threadIdx.x >> 6, l = threadIdx.x & 63;
    const int r = blockIdx.x * 4 + w;                    // 0..16383
    const float2 wh = *(const float2*)(Wh + (size_t)r * FO_ + l * 2);
    const float2 as = *(const float2*)(aw + l * 2);
    const float2 ad = *(const float2*)(aw + FO_ + l * 2);
    float sp  = wh.x * as.x + wh.y * as.y;
    float dpv = wh.x * ad.x + wh.y * ad.y;
    #pragma unroll
    for (int off = 32; off >= 1; off >>= 1) {
        sp  += __shfl_xor(sp, off);
        dpv += __shfl_xor(dpv, off);
    }
    if (l == 0) {
        srcv[r] = sp;
        float db = dpv + ab[0];                          // dst_j + a_b
        dstbv[r] = db;
        e1v[r] = __expf(db);
        e2v[r] = __expf(0.01f * db);
        unsigned u = __float_as_uint(db);
        u = (u & 0x80000000u) ? ~u : (u | 0x80000000u);  // order-preserving
        atomicMax(&maxenc[r >> 12], u);
    }
}

// ---------------- K3: fused mask+softmax+PV, rank-1 + exp-free inner -----
// grid (512, SPLIT); block 4 waves: rt=w>>1 rows, ch=w&1 cols
__global__ __launch_bounds__(256) void k3_gat(
    const int* __restrict__ adj, const __hip_bfloat16* __restrict__ WhT,
    const float* __restrict__ srcv, const float* __restrict__ dstbv,
    const float* __restrict__ e1v, const float* __restrict__ e2v,
    const unsigned* __restrict__ maxenc, float* __restrict__ out,
    float* __restrict__ pacc, float* __restrict__ prow)
{
    const int tid = threadIdx.x;
    const int w = tid >> 6, l = tid & 63;
    const int rt = w >> 1, ch = w & 1;
    const int lr = l & 15, g = l >> 4;
    const int blk = blockIdx.x;
    const int b = blk >> 7;
    const int i_base = (blk & 127) * 32 + rt * 16;       // row base in batch
    const int myrow = i_base + lr;

    const int nsplit = gridDim.y;
    const int steps = NSTEP / nsplit;
    const int j0 = blockIdx.y * steps * 32;              // column offset
    const bool final = (nsplit == 1);

    const float sm = srcv[b * N_ + myrow];
    const unsigned venc = maxenc[b];
    const unsigned ud = (venc & 0x80000000u) ? (venc ^ 0x80000000u) : ~venc;
    const float mdb = __uint_as_float(ud);               // max_j (dst_j+a_b)
    const float eub = sm + mdb;
    const float m = fmaxf(eub, 0.01f * eub);             // >= row max of LR(e)
    const float C1 = __expf(sm - m);
    const float C2 = __expf(0.01f * sm - m);
    const float T = -sm;                                 // e>=0 <=> db >= T

    const int* adjp = adj + ((size_t)b * N_ + myrow) * N_ + j0 + g * 8;
    const float* dp  = dstbv + (size_t)b * N_ + j0 + g * 8;
    const float* e1p = e1v   + (size_t)b * N_ + j0 + g * 8;
    const float* e2p = e2v   + (size_t)b * N_ + j0 + g * 8;
    const __hip_bfloat16* wp = WhT + ((size_t)b * FO_ + ch * 64 + lr) * N_ + j0 + g * 8;

    f32x4 acc0 = (f32x4)0.f, acc1 = (f32x4)0.f, acc2 = (f32x4)0.f,
          acc3 = (f32x4)0.f, accl = (f32x4)0.f;
    s16x8 ones;
    { union { s16x8 v; unsigned u[4]; } o;
      o.u[0] = o.u[1] = o.u[2] = o.u[3] = 0x3F803F80u; ones = o.v; }

    #pragma unroll 2
    for (int t = 0; t < steps; ++t) {
        const int j = t * 32;
        int4  a0 = *(const int4*)(adjp + j);
        int4  a1 = *(const int4*)(adjp + j + 4);
        f32x4 d0 = *(const f32x4*)(dp + j);
        f32x4 d1 = *(const f32x4*)(dp + j + 4);
        f32x4 x0 = *(const f32x4*)(e1p + j);
        f32x4 x1 = *(const f32x4*)(e1p + j + 4);
        f32x4 y0 = *(const f32x4*)(e2p + j);
        f32x4 y1 = *(const f32x4*)(e2p + j + 4);
        s16x8 w0 = *(const s16x8*)(wp + j);
        s16x8 w1 = *(const s16x8*)(wp + 16 * N_ + j);
        s16x8 w2 = *(const s16x8*)(wp + 32 * N_ + j);
        s16x8 w3 = *(const s16x8*)(wp + 48 * N_ + j);

        float p[8];
        #pragma unroll
        for (int u2 = 0; u2 < 4; ++u2) {
            float pe0 = (d0[u2] >= T) ? C1 * x0[u2] : C2 * y0[u2];
            p[u2]     = ((&a0.x)[u2] > 0) ? pe0 : 0.0f;
            float pe1 = (d1[u2] >= T) ? C1 * x1[u2] : C2 * y1[u2];
            p[4 + u2] = ((&a1.x)[u2] > 0) ? pe1 : 0.0f;
        }
        union { s16x8 v; unsigned u[4]; } af;
        af.u[0] = pkbf(p[0], p[1]); af.u[1] = pkbf(p[2], p[3]);
        af.u[2] = pkbf(p[4], p[5]); af.u[3] = pkbf(p[6], p[7]);

        accl = __builtin_amdgcn_mfma_f32_16x16x32_bf16(af.v, ones, accl, 0, 0, 0);
        acc0 = __builtin_amdgcn_mfma_f32_16x16x32_bf16(af.v, w0, acc0, 0, 0, 0);
        acc1 = __builtin_amdgcn_mfma_f32_16x16x32_bf16(af.v, w1, acc1, 0, 0, 0);
        acc2 = __builtin_amdgcn_mfma_f32_16x16x32_bf16(af.v, w2, acc2, 0, 0, 0);
        acc3 = __builtin_amdgcn_mfma_f32_16x16x32_bf16(af.v, w3, acc3, 0, 0, 0);
    }

    if (final) {
        #pragma unroll
        for (int kk = 0; kk < 4; ++kk) {
            float inv = 1.0f / accl[kk];
            int row = i_base + g * 4 + kk;
            float* op = out + ((size_t)b * N_ + row) * FO_ + ch * 64 + lr;
            op[0]  = acc0[kk] * inv;
            op[16] = acc1[kk] * inv;
            op[32] = acc2[kk] * inv;
            op[48] = acc3[kk] * inv;
        }
    } else {
        const size_t sb = (size_t)blockIdx.y * ((size_t)NROWS * FO_);
        #pragma unroll
        for (int kk = 0; kk < 4; ++kk) {
            int grow = b * N_ + i_base + g * 4 + kk;
            float* pp = pacc + sb + (size_t)grow * FO_ + ch * 64 + lr;
            pp[0]  = acc0[kk];
            pp[16] = acc1[kk];
            pp[32] = acc2[kk];
            pp[48] = acc3[kk];
            if (ch == 0) prow[blockIdx.y * NROWS + grow] = accl[kk];
        }
    }
}

// ---------------- K4: combine split partials + normalize -----------------
__global__ __launch_bounds__(256) void k4_comb(
    const float* __restrict__ pacc, const float* __restrict__ prow,
    float* __restrict__ out, int nsplit)
{
    const int idx = blockIdx.x * 256 + threadIdx.x;      // 2,097,152
    const int grow = idx >> 7;
    float s = 0.f, rs = 0.f;
    for (int si = 0; si < nsplit; ++si) {
        s  += pacc[(size_t)si * ((size_t)NROWS * FO_) + idx];
        rs += prow[si * NROWS + grow];
    }
    out[idx] = s / rs;
}

extern "C" void kernel_launch(void* const* d_in, const int* in_sizes, int n_in,
                              void* d_out, int out_size, void* d_ws, size_t ws_size,
                              hipStream_t stream)
{
    const float* h  = (const float*)d_in[0];
    const int* adj  = (const int*)d_in[1];
    const float* Ww = (const float*)d_in[2];
    const float* Wb = (const float*)d_in[3];
    const float* aw = (const float*)d_in[4];
    const float* ab = (const float*)d_in[5];
    float* out = (float*)d_out;

    char* wsb = (char*)d_ws;
    float* Wh            = (float*)wsb;                               // 8 MB
    __hip_bfloat16* WhT  = (__hip_bfloat16*)(wsb + (8u << 20));       // 4 MB
    char* aux            = wsb + (12u << 20);
    float* srcv          = (float*)(aux);
    float* dstbv         = (float*)(aux + (64u << 10));
    float* e1v           = (float*)(aux + (128u << 10));
    float* e2v           = (float*)(aux + (192u << 10));
    __hip_bfloat16* whi  = (__hip_bfloat16*)(aux + (256u << 10));
    __hip_bfloat16* wlo  = (__hip_bfloat16*)(aux + (320u << 10));
    unsigned* maxenc     = (unsigned*)(aux + (384u << 10));
    float* pacc          = (float*)(wsb + (13u << 20));               // SPLIT*8 MB
    float* prow          = (float*)(wsb + (13u << 20) + (SIZE_MAX & 0)); // set below

    // pick SPLIT by available workspace
    const size_t paccBytes1 = (size_t)NROWS * FO_ * 4;   // 8 MB per split
    const size_t prowBytes1 = (size_t)NROWS * 4;         // 64 KB per split
    int SPLIT = 1;
    if (ws_size >= (13u << 20) + 4 * paccBytes1 + 4 * prowBytes1) SPLIT = 4;
    else if (ws_size >= (13u << 20) + 2 * paccBytes1 + 2 * prowBytes1) SPLIT = 2;
    prow = (float*)(wsb + (13u << 20) + (size_t)SPLIT * paccBytes1);

    hipMemsetAsync(maxenc, 0, NB_ * sizeof(unsigned), stream);
    k0_packw<<<128, 256, 0, stream>>>(Ww, whi, wlo);
    k1_wh<<<1024, 256, 0, stream>>>(h, whi, wlo, Wb, Wh, WhT);
    k2_vec<<<4096, 256, 0, stream>>>(Wh, aw, ab, srcv, dstbv, e1v, e2v, maxenc);
    dim3 g3(512, SPLIT);
    k3_gat<<<g3, 256, 0, stream>>>(adj, WhT, srcv, dstbv, e1v, e2v, maxenc, out, pacc, prow);
    if (SPLIT > 1)
        k4_comb<<<(NROWS * FO_) / 256, 256, 0, stream>>>(pacc, prow, out, SPLIT);
}

// Round 3
// 294.205 us; speedup vs baseline: 1.5755x; 1.5755x over previous
//
#include <hip/hip_runtime.h>
#include <hip/hip_bf16.h>

typedef __attribute__((ext_vector_type(4))) float f32x4;
typedef __attribute__((ext_vector_type(8))) short s16x8;

#define NB_ 4
#define N_ 4096
#define FI_ 256
#define FO_ 128
#define PHC 64            // adj cols per phase
#define NPH (N_ / PHC)    // 64 phases

// pack two f32 -> one u32 of 2 bf16 (RNE), first arg in low half
__device__ __forceinline__ unsigned pkbf(float a, float b) {
    __hip_bfloat162 t = __float22bfloat162_rn(make_float2(a, b));
    unsigned r; __builtin_memcpy(&r, &t, 4); return r;
}

typedef __attribute__((address_space(1))) const void CGV;
typedef __attribute__((address_space(3))) void LDSV;
__device__ __forceinline__ void gload16(const void* g, void* l) {
    __builtin_amdgcn_global_load_lds((CGV*)g, (LDSV*)l, 16, 0, 0);
}

// ---------------- K0: pack W into bf16 hi/lo ----------------------------
__global__ __launch_bounds__(256) void k0_packw(
    const float* __restrict__ Ww, __hip_bfloat16* __restrict__ whi,
    __hip_bfloat16* __restrict__ wlo)
{
    int idx = blockIdx.x * 256 + threadIdx.x;           // 32768 elems
    float v = Ww[idx];
    __hip_bfloat16 hi = __float2bfloat16(v);
    whi[idx] = hi;
    wlo[idx] = __float2bfloat16(v - __bfloat162float(hi));
}

// ---------------- K1: Wh = h @ W^T + Wb  (split-bf16, 3 MFMA) -----------
__global__ __launch_bounds__(256) void k1_wh(
    const float* __restrict__ h, const __hip_bfloat16* __restrict__ whi,
    const __hip_bfloat16* __restrict__ wlo, const float* __restrict__ Wb,
    float* __restrict__ Wh)
{
    const int tid = threadIdx.x;
    const int w = tid >> 6, l = tid & 63;
    const int lr = l & 15, g = l >> 4;
    const int r0 = blockIdx.x * 16;
    const float* hp = h + (size_t)(r0 + lr) * FI_ + g * 8;

    f32x4 acc[2] = {(f32x4)0.f, (f32x4)0.f};

    #pragma unroll
    for (int kt = 0; kt < 8; ++kt) {
        f32x4 x0 = *(const f32x4*)(hp + kt * 32);
        f32x4 x1 = *(const f32x4*)(hp + kt * 32 + 4);
        float xx[8];
        #pragma unroll
        for (int t = 0; t < 4; ++t) { xx[t] = x0[t]; xx[t + 4] = x1[t]; }
        union { s16x8 v; unsigned u[4]; } ahi, alo;
        #pragma unroll
        for (int t = 0; t < 4; ++t) {
            float a0 = xx[2 * t], a1 = xx[2 * t + 1];
            unsigned uh = pkbf(a0, a1);
            ahi.u[t] = uh;
            float h0f = __uint_as_float(uh << 16);
            float h1f = __uint_as_float(uh & 0xffff0000u);
            alo.u[t] = pkbf(a0 - h0f, a1 - h1f);
        }
        #pragma unroll
        for (int c = 0; c < 2; ++c) {
            const int o = w * 32 + c * 16 + lr;
            s16x8 bh = *(const s16x8*)(whi + (size_t)o * FI_ + kt * 32 + g * 8);
            s16x8 bl = *(const s16x8*)(wlo + (size_t)o * FI_ + kt * 32 + g * 8);
            acc[c] = __builtin_amdgcn_mfma_f32_16x16x32_bf16(ahi.v, bh, acc[c], 0, 0, 0);
            acc[c] = __builtin_amdgcn_mfma_f32_16x16x32_bf16(alo.v, bh, acc[c], 0, 0, 0);
            acc[c] = __builtin_amdgcn_mfma_f32_16x16x32_bf16(ahi.v, bl, acc[c], 0, 0, 0);
        }
    }

    #pragma unroll
    for (int c = 0; c < 2; ++c) {
        int col = w * 32 + c * 16 + lr;
        float wb = Wb[col];
        #pragma unroll
        for (int kk = 0; kk < 4; ++kk) {
            int grow = r0 + g * 4 + kk;
            Wh[(size_t)grow * FO_ + col] = acc[c][kk] + wb;
        }
    }
}

// ---------------- K1t: transpose Wh -> WhT bf16 [b][o][n] ---------------
__global__ __launch_bounds__(256) void k1t(
    const float* __restrict__ Wh, __hip_bfloat16* __restrict__ WhT)
{
    __shared__ __hip_bfloat16 lds[64][130];
    const int t = threadIdx.x;
    const int r0 = blockIdx.x * 64;                      // 256 blocks
    {
        int row = t >> 2, cs = (t & 3) * 32;
        const float* src = Wh + (size_t)(r0 + row) * FO_ + cs;
        #pragma unroll
        for (int i = 0; i < 8; ++i) {
            f32x4 v = *(const f32x4*)(src + i * 4);
            #pragma unroll
            for (int u2 = 0; u2 < 4; ++u2)
                lds[row][cs + i * 4 + u2] = __float2bfloat16(v[u2]);
        }
    }
    __syncthreads();
    {
        int o = t >> 1, nh = (t & 1) * 32;
        int bb = r0 >> 12, nn = r0 & 4095;
        __hip_bfloat16* dst = WhT + ((size_t)bb * FO_ + o) * N_ + nn + nh;
        __hip_bfloat16 tmp[32];
        #pragma unroll
        for (int i = 0; i < 32; ++i) tmp[i] = lds[nh + i][o];
        #pragma unroll
        for (int i = 0; i < 4; ++i) {
            s16x8 v; __builtin_memcpy(&v, tmp + i * 8, 16);
            *(s16x8*)(dst + i * 8) = v;
        }
    }
}

// ---------------- K2: per-row src/dst + exp tables (no atomics) ---------
__global__ __launch_bounds__(256) void k2_vec(
    const float* __restrict__ Wh, const float* __restrict__ aw,
    const float* __restrict__ ab, float* __restrict__ srcv,
    float* __restrict__ dstbv, float* __restrict__ e1v,
    float* __restrict__ e2v)
{
    const int w = threadIdx.x >> 6, l = threadIdx.x & 63;
    const int r = blockIdx.x * 4 + w;                    // 0..16383
    const float2 wh = *(const float2*)(Wh + (size_t)r * FO_ + l * 2);
    const float2 as = *(const float2*)(aw + l * 2);
    const float2 ad = *(const float2*)(aw + FO_ + l * 2);
    float sp  = wh.x * as.x + wh.y * as.y;
    float dpv = wh.x * ad.x + wh.y * ad.y;
    #pragma unroll
    for (int off = 32; off >= 1; off >>= 1) {
        sp  += __shfl_xor(sp, off);
        dpv += __shfl_xor(dpv, off);
    }
    if (l == 0) {
        srcv[r] = sp;
        float db = dpv + ab[0];                          // dst_j + a_b
        dstbv[r] = db;
        e1v[r] = __expf(db);
        e2v[r] = __expf(0.01f * db);
    }
}

// ---------------- K2b: per-batch max of dstbv (tree reduce) -------------
__global__ __launch_bounds__(256) void k2b_max(
    const float* __restrict__ dstbv, float* __restrict__ maxv)
{
    const int b = blockIdx.x;
    const int t = threadIdx.x, w = t >> 6, l = t & 63;
    float m = -3.4e38f;
    for (int i = t; i < N_; i += 256) m = fmaxf(m, dstbv[b * N_ + i]);
    #pragma unroll
    for (int off = 32; off >= 1; off >>= 1) m = fmaxf(m, __shfl_xor(m, off));
    __shared__ float red[4];
    if (l == 0) red[w] = m;
    __syncthreads();
    if (t == 0) maxv[b] = fmaxf(fmaxf(red[0], red[1]), fmaxf(red[2], red[3]));
}

// ---------------- K3: fused mask+softmax+PV, 2-phase LDS pipeline -------
// 256 blocks (b*64 + rowblk), 128 threads = 2 waves, wave = 32 rows x 128 o
__global__ __launch_bounds__(128) void k3_gat(
    const int* __restrict__ adj, const __hip_bfloat16* __restrict__ WhT,
    const float* __restrict__ srcv, const float* __restrict__ dstbv,
    const float* __restrict__ e1v, const float* __restrict__ e2v,
    const float* __restrict__ maxv, float* __restrict__ out)
{
    __shared__ int            adjbuf[2][64 * 64];        // 32 KB, chunk-swizzled
    __shared__ __hip_bfloat16 whbuf[2][128 * 64];        // 32 KB, chunk-swizzled
    __shared__ float          auxbuf[2][3 * 64];         // d | e1 | e2

    const int t = threadIdx.x;
    const int w = t >> 6, l = t & 63;
    const int lr = l & 15, g = l >> 4;
    const int b = blockIdx.x >> 6;
    const int rbase = (blockIdx.x & 63) * 64;

    float C1[2], C2[2], T[2];
    {
        const float mdb = maxv[b];
        #pragma unroll
        for (int rt = 0; rt < 2; ++rt) {
            int r = rbase + w * 32 + rt * 16 + lr;
            float s = srcv[b * N_ + r];
            float eub = s + mdb;
            float m = fmaxf(eub, 0.01f * eub);           // >= row max of LR(e)
            C1[rt] = __expf(s - m);
            C2[rt] = __expf(0.01f * s - m);
            T[rt] = -s;
        }
    }

    const int* abase = adj + ((size_t)b * N_ + rbase) * N_;
    const __hip_bfloat16* wtb = WhT + (size_t)b * FO_ * N_;
    const float* dpb  = dstbv + (size_t)b * N_;
    const float* x1b  = e1v + (size_t)b * N_;
    const float* x2b  = e2v + (size_t)b * N_;

    f32x4 acc[2][8];
    f32x4 accl[2];
    #pragma unroll
    for (int rt = 0; rt < 2; ++rt) {
        accl[rt] = (f32x4)0.f;
        #pragma unroll
        for (int ot = 0; ot < 8; ++ot) acc[rt][ot] = (f32x4)0.f;
    }
    s16x8 ones;
    { union { s16x8 v; unsigned u[4]; } o;
      o.u[0] = o.u[1] = o.u[2] = o.u[3] = 0x3F803F80u; ones = o.v; }

    // ---- stage one phase into buffer bi (fire-and-forget DMA) ----
    auto stage = [&](int bi, int ph) {
        const int jb = ph * PHC;
        // adj tile: 1024 slots x 16B; slot s -> row=s>>4, chunk c=s&15,
        // LDS slot c holds global chunk c^(row&7)
        #pragma unroll
        for (int i = 0; i < 8; ++i) {
            int s = i * 128 + t;
            int row = s >> 4, c = s & 15;
            gload16(abase + (size_t)row * N_ + jb + ((c ^ (row & 7)) << 2),
                    &adjbuf[bi][(i * 128 + w * 64) * 4]);
        }
        // WhT tile: 1024 slots x 16B; slot s -> o=s>>3, chunk c=s&7
        #pragma unroll
        for (int i = 0; i < 8; ++i) {
            int s = i * 128 + t;
            int o = s >> 3, c = s & 7;
            gload16(wtb + (size_t)o * N_ + jb + ((c ^ (o & 7)) << 3),
                    &whbuf[bi][(i * 128 + w * 64) * 8]);
        }
        // aux: 48 slots of 16B (d, e1, e2), wave 0 lanes 0..47 only
        if (t < 48) {
            int a = t >> 4, c = t & 15;
            const float* src = (a == 0 ? dpb : (a == 1 ? x1b : x2b)) + jb + c * 4;
            gload16(src, &auxbuf[bi][0]);
        }
    };

    stage(0, 0);
    __syncthreads();
    int cur = 0;

    for (int ph = 0; ph < NPH; ++ph) {
        if (ph + 1 < NPH) stage(cur ^ 1, ph + 1);

        #pragma unroll
        for (int sub = 0; sub < 2; ++sub) {
            const int jl = sub * 32 + g * 8;
            f32x4 d0 = *(const f32x4*)&auxbuf[cur][jl];
            f32x4 d1 = *(const f32x4*)&auxbuf[cur][jl + 4];
            f32x4 x0 = *(const f32x4*)&auxbuf[cur][64 + jl];
            f32x4 x1 = *(const f32x4*)&auxbuf[cur][64 + jl + 4];
            f32x4 y0 = *(const f32x4*)&auxbuf[cur][128 + jl];
            f32x4 y1 = *(const f32x4*)&auxbuf[cur][128 + jl + 4];

            s16x8 Bf[8];
            #pragma unroll
            for (int ot = 0; ot < 8; ++ot) {
                int o = ot * 16 + lr;
                int c = (sub * 4 + g) ^ (o & 7);
                Bf[ot] = *(const s16x8*)&whbuf[cur][o * 64 + c * 8];
            }
            #pragma unroll
            for (int rt = 0; rt < 2; ++rt) {
                int row = w * 32 + rt * 16 + lr;
                int cb = sub * 8 + g * 2;
                int4 a0 = *(const int4*)&adjbuf[cur][row * 64 + ((cb ^ (row & 7)) << 2)];
                int4 a1 = *(const int4*)&adjbuf[cur][row * 64 + (((cb + 1) ^ (row & 7)) << 2)];
                float p[8];
                #pragma unroll
                for (int u2 = 0; u2 < 4; ++u2) {
                    float pe0 = (d0[u2] >= T[rt]) ? C1[rt] * x0[u2] : C2[rt] * y0[u2];
                    p[u2]     = ((&a0.x)[u2] > 0) ? pe0 : 0.0f;
                    float pe1 = (d1[u2] >= T[rt]) ? C1[rt] * x1[u2] : C2[rt] * y1[u2];
                    p[4 + u2] = ((&a1.x)[u2] > 0) ? pe1 : 0.0f;
                }
                union { s16x8 v; unsigned u[4]; } af;
                af.u[0] = pkbf(p[0], p[1]); af.u[1] = pkbf(p[2], p[3]);
                af.u[2] = pkbf(p[4], p[5]); af.u[3] = pkbf(p[6], p[7]);

                accl[rt] = __builtin_amdgcn_mfma_f32_16x16x32_bf16(af.v, ones, accl[rt], 0, 0, 0);
                #pragma unroll
                for (int ot = 0; ot < 8; ++ot)
                    acc[rt][ot] = __builtin_amdgcn_mfma_f32_16x16x32_bf16(af.v, Bf[ot], acc[rt][ot], 0, 0, 0);
            }
        }
        __syncthreads();   // drains stage(ph+1) DMA; waves done reading buf[cur]
        cur ^= 1;
    }

    #pragma unroll
    for (int rt = 0; rt < 2; ++rt) {
        #pragma unroll
        for (int kk = 0; kk < 4; ++kk) {
            float inv = 1.0f / accl[rt][kk];
            int row = rbase + w * 32 + rt * 16 + g * 4 + kk;
            float* op = out + ((size_t)b * N_ + row) * FO_ + lr;
            #pragma unroll
            for (int ot = 0; ot < 8; ++ot)
                op[ot * 16] = acc[rt][ot][kk] * inv;
        }
    }
}

extern "C" void kernel_launch(void* const* d_in, const int* in_sizes, int n_in,
                              void* d_out, int out_size, void* d_ws, size_t ws_size,
                              hipStream_t stream)
{
    const float* h  = (const float*)d_in[0];
    const int* adj  = (const int*)d_in[1];
    const float* Ww = (const float*)d_in[2];
    const float* Wb = (const float*)d_in[3];
    const float* aw = (const float*)d_in[4];
    const float* ab = (const float*)d_in[5];
    float* out = (float*)d_out;

    char* wsb = (char*)d_ws;
    float* Wh            = (float*)wsb;                               // 8 MB
    __hip_bfloat16* WhT  = (__hip_bfloat16*)(wsb + (8u << 20));       // 4 MB
    char* aux            = wsb + (12u << 20);
    float* srcv          = (float*)(aux);                             // 64 KB
    float* dstbv         = (float*)(aux + (64u << 10));
    float* e1v           = (float*)(aux + (128u << 10));
    float* e2v           = (float*)(aux + (192u << 10));
    __hip_bfloat16* whi  = (__hip_bfloat16*)(aux + (256u << 10));
    __hip_bfloat16* wlo  = (__hip_bfloat16*)(aux + (320u << 10));
    float* maxv          = (float*)(aux + (384u << 10));              // 16 B

    k0_packw<<<128, 256, 0, stream>>>(Ww, whi, wlo);
    k1_wh<<<1024, 256, 0, stream>>>(h, whi, wlo, Wb, Wh);
    k1t<<<256, 256, 0, stream>>>(Wh, WhT);
    k2_vec<<<4096, 256, 0, stream>>>(Wh, aw, ab, srcv, dstbv, e1v, e2v);
    k2b_max<<<4, 256, 0, stream>>>(dstbv, maxv);
    k3_gat<<<256, 128, 0, stream>>>(adj, WhT, srcv, dstbv, e1v, e2v, maxv, out);
}

// Round 4
// 166.059 us; speedup vs baseline: 2.7913x; 1.7717x over previous
//
#include <hip/hip_runtime.h>
#include <hip/hip_bf16.h>

typedef __attribute__((ext_vector_type(4))) float f32x4;
typedef __attribute__((ext_vector_type(8))) short s16x8;
typedef unsigned long long u64;

#define NB_ 4
#define N_ 4096
#define FI_ 256
#define FO_ 128
#define NROWS 16384       // NB_ * N_
#define SPLIT 4
#define PHC 64            // cols per phase
#define PHN ((N_ / SPLIT) / PHC)   // 16 phases per block

// pack two f32 -> one u32 of 2 bf16 (RNE), first arg in low half
__device__ __forceinline__ unsigned pkbf(float a, float b) {
    __hip_bfloat162 t = __float22bfloat162_rn(make_float2(a, b));
    unsigned r; __builtin_memcpy(&r, &t, 4); return r;
}

typedef __attribute__((address_space(1))) const void CGV;
typedef __attribute__((address_space(3))) void LDSV;
__device__ __forceinline__ void gload16(const void* g, void* l) {
    __builtin_amdgcn_global_load_lds((CGV*)g, (LDSV*)l, 16, 0, 0);
}

// ---------------- K_adjb: adj (268MB) -> bitmask (8.4MB), pure stream ----
__global__ __launch_bounds__(256) void k_adjb(
    const int* __restrict__ adj, u64* __restrict__ bits)
{
    const int t = threadIdx.x;
    const int w = t >> 6, l = t & 63;
    const int row = blockIdx.x * 4 + w;                  // 0..16383
    const int* ar = adj + (size_t)row * N_;
    u64* br = bits + (size_t)row * 64;
    #pragma unroll 2
    for (int s = 0; s < 64; s += 4) {
        int v0 = ar[(s + 0) * 64 + l];
        int v1 = ar[(s + 1) * 64 + l];
        int v2 = ar[(s + 2) * 64 + l];
        int v3 = ar[(s + 3) * 64 + l];
        u64 b0 = __ballot(v0 > 0);
        u64 b1 = __ballot(v1 > 0);
        u64 b2 = __ballot(v2 > 0);
        u64 b3 = __ballot(v3 > 0);
        if (l == 0) { br[s] = b0; br[s + 1] = b1; br[s + 2] = b2; br[s + 3] = b3; }
    }
}

// ---------------- K0: pack W into bf16 hi/lo ----------------------------
__global__ __launch_bounds__(256) void k0_packw(
    const float* __restrict__ Ww, __hip_bfloat16* __restrict__ whi,
    __hip_bfloat16* __restrict__ wlo)
{
    int idx = blockIdx.x * 256 + threadIdx.x;           // 32768 elems
    float v = Ww[idx];
    __hip_bfloat16 hi = __float2bfloat16(v);
    whi[idx] = hi;
    wlo[idx] = __float2bfloat16(v - __bfloat162float(hi));
}

// ---------------- K1: Wh = h @ W^T + Wb  (split-bf16, 3 MFMA) -----------
__global__ __launch_bounds__(256) void k1_wh(
    const float* __restrict__ h, const __hip_bfloat16* __restrict__ whi,
    const __hip_bfloat16* __restrict__ wlo, const float* __restrict__ Wb,
    float* __restrict__ Wh)
{
    const int tid = threadIdx.x;
    const int w = tid >> 6, l = tid & 63;
    const int lr = l & 15, g = l >> 4;
    const int r0 = blockIdx.x * 16;
    const float* hp = h + (size_t)(r0 + lr) * FI_ + g * 8;

    f32x4 acc[2] = {(f32x4)0.f, (f32x4)0.f};

    #pragma unroll
    for (int kt = 0; kt < 8; ++kt) {
        f32x4 x0 = *(const f32x4*)(hp + kt * 32);
        f32x4 x1 = *(const f32x4*)(hp + kt * 32 + 4);
        float xx[8];
        #pragma unroll
        for (int t = 0; t < 4; ++t) { xx[t] = x0[t]; xx[t + 4] = x1[t]; }
        union { s16x8 v; unsigned u[4]; } ahi, alo;
        #pragma unroll
        for (int t = 0; t < 4; ++t) {
            float a0 = xx[2 * t], a1 = xx[2 * t + 1];
            unsigned uh = pkbf(a0, a1);
            ahi.u[t] = uh;
            float h0f = __uint_as_float(uh << 16);
            float h1f = __uint_as_float(uh & 0xffff0000u);
            alo.u[t] = pkbf(a0 - h0f, a1 - h1f);
        }
        #pragma unroll
        for (int c = 0; c < 2; ++c) {
            const int o = w * 32 + c * 16 + lr;
            s16x8 bh = *(const s16x8*)(whi + (size_t)o * FI_ + kt * 32 + g * 8);
            s16x8 bl = *(const s16x8*)(wlo + (size_t)o * FI_ + kt * 32 + g * 8);
            acc[c] = __builtin_amdgcn_mfma_f32_16x16x32_bf16(ahi.v, bh, acc[c], 0, 0, 0);
            acc[c] = __builtin_amdgcn_mfma_f32_16x16x32_bf16(alo.v, bh, acc[c], 0, 0, 0);
            acc[c] = __builtin_amdgcn_mfma_f32_16x16x32_bf16(ahi.v, bl, acc[c], 0, 0, 0);
        }
    }

    #pragma unroll
    for (int c = 0; c < 2; ++c) {
        int col = w * 32 + c * 16 + lr;
        float wb = Wb[col];
        #pragma unroll
        for (int kk = 0; kk < 4; ++kk) {
            int grow = r0 + g * 4 + kk;
            Wh[(size_t)grow * FO_ + col] = acc[c][kk] + wb;
        }
    }
}

// ---------------- K1t: transpose Wh -> WhT bf16 [b][o][n] ---------------
__global__ __launch_bounds__(256) void k1t(
    const float* __restrict__ Wh, __hip_bfloat16* __restrict__ WhT)
{
    __shared__ __hip_bfloat16 lds[64][130];
    const int t = threadIdx.x;
    const int r0 = blockIdx.x * 64;                      // 256 blocks
    {
        int row = t >> 2, cs = (t & 3) * 32;
        const float* src = Wh + (size_t)(r0 + row) * FO_ + cs;
        #pragma unroll
        for (int i = 0; i < 8; ++i) {
            f32x4 v = *(const f32x4*)(src + i * 4);
            #pragma unroll
            for (int u2 = 0; u2 < 4; ++u2)
                lds[row][cs + i * 4 + u2] = __float2bfloat16(v[u2]);
        }
    }
    __syncthreads();
    {
        int o = t >> 1, nh = (t & 1) * 32;
        int bb = r0 >> 12, nn = r0 & 4095;
        __hip_bfloat16* dst = WhT + ((size_t)bb * FO_ + o) * N_ + nn + nh;
        __hip_bfloat16 tmp[32];
        #pragma unroll
        for (int i = 0; i < 32; ++i) tmp[i] = lds[nh + i][o];
        #pragma unroll
        for (int i = 0; i < 4; ++i) {
            s16x8 v; __builtin_memcpy(&v, tmp + i * 8, 16);
            *(s16x8*)(dst + i * 8) = v;
        }
    }
}

// ---------------- K2: per-row src/dst + exp tables ----------------------
__global__ __launch_bounds__(256) void k2_vec(
    const float* __restrict__ Wh, const float* __restrict__ aw,
    const float* __restrict__ ab, float* __restrict__ srcv,
    float* __restrict__ dstbv, float* __restrict__ e1v,
    float* __restrict__ e2v)
{
    const int w = threadIdx.x >> 6, l = threadIdx.x & 63;
    const int r = blockIdx.x * 4 + w;                    // 0..16383
    const float2 wh = *(const float2*)(Wh + (size_t)r * FO_ + l * 2);
    const float2 as = *(const float2*)(aw + l * 2);
    const float2 ad = *(const float2*)(aw + FO_ + l * 2);
    float sp  = wh.x * as.x + wh.y * as.y;
    float dpv = wh.x * ad.x + wh.y * ad.y;
    #pragma unroll
    for (int off = 32; off >= 1; off >>= 1) {
        sp  += __shfl_xor(sp, off);
        dpv += __shfl_xor(dpv, off);
    }
    if (l == 0) {
        srcv[r] = sp;
        float db = dpv + ab[0];                          // dst_j + a_b
        dstbv[r] = db;
        e1v[r] = __expf(db);
        e2v[r] = __expf(0.01f * db);
    }
}

// ---------------- K2b: per-batch max of dstbv ---------------------------
__global__ __launch_bounds__(256) void k2b_max(
    const float* __restrict__ dstbv, float* __restrict__ maxv)
{
    const int b = blockIdx.x;
    const int t = threadIdx.x, w = t >> 6, l = t & 63;
    float m = -3.4e38f;
    for (int i = t; i < N_; i += 256) m = fmaxf(m, dstbv[b * N_ + i]);
    #pragma unroll
    for (int off = 32; off >= 1; off >>= 1) m = fmaxf(m, __shfl_xor(m, off));
    __shared__ float red[4];
    if (l == 0) red[w] = m;
    __syncthreads();
    if (t == 0) maxv[b] = fmaxf(fmaxf(red[0], red[1]), fmaxf(red[2], red[3]));
}

// ---------------- K3: bitmask-masked softmax+PV, split over columns -----
// grid (256, SPLIT): x = b*64 + rowblk(64 rows); 4 waves x 16 rows x 128 o
__global__ __launch_bounds__(256, 4) void k3_gat(
    const u64* __restrict__ bits, const __hip_bfloat16* __restrict__ WhT,
    const float* __restrict__ srcv, const float* __restrict__ dstbv,
    const float* __restrict__ e1v, const float* __restrict__ e2v,
    const float* __restrict__ maxv, float* __restrict__ pacc,
    float* __restrict__ prow)
{
    __shared__ __hip_bfloat16 whbuf[2][128 * 64];        // 2 x 16 KB, swizzled
    __shared__ float auxbuf[2][192];                     // d | e1 | e2

    const int t = threadIdx.x;
    const int w = t >> 6, l = t & 63;
    const int lr = l & 15, g = l >> 4;
    const int b = blockIdx.x >> 6;
    const int rbase = (blockIdx.x & 63) * 64 + w * 16;   // wave row base (in batch)
    const int myrow = rbase + lr;
    const int j0 = blockIdx.y * (N_ / SPLIT);

    float C1, C2, T;
    {
        float s = srcv[b * N_ + myrow];
        float eub = s + maxv[b];
        float m = fmaxf(eub, 0.01f * eub);               // >= row max of LR(e)
        C1 = __expf(s - m);
        C2 = __expf(0.01f * s - m);
        T = -s;                                          // e>=0 <=> db >= T
    }

    const __hip_bfloat16* wtb = WhT + (size_t)b * FO_ * N_ + j0;
    const float* dpb = dstbv + (size_t)b * N_ + j0;
    const float* x1b = e1v   + (size_t)b * N_ + j0;
    const float* x2b = e2v   + (size_t)b * N_ + j0;
    const u64* bitp  = bits + (size_t)(b * N_ + myrow) * 64 + (j0 >> 6);

    f32x4 acc[8];
    f32x4 accl = (f32x4)0.f;
    #pragma unroll
    for (int ot = 0; ot < 8; ++ot) acc[ot] = (f32x4)0.f;
    s16x8 ones;
    { union { s16x8 v; unsigned u[4]; } o;
      o.u[0] = o.u[1] = o.u[2] = o.u[3] = 0x3F803F80u; ones = o.v; }

    auto stage = [&](int bi, int ph) {
        const int jb = ph * PHC;
        #pragma unroll
        for (int i = 0; i < 4; ++i) {                    // 1024 slots x 16B
            int s = i * 256 + t;
            int o = s >> 3, c = s & 7;                   // chunk swizzle (T2)
            gload16(wtb + (size_t)o * N_ + jb + ((c ^ (o & 7)) << 3),
                    &whbuf[bi][(i * 256 + w * 64) * 8]);
        }
        if (t < 48) {                                    // 768 B aux
            int a = t >> 4, c = t & 15;
            const float* src = (a == 0 ? dpb : (a == 1 ? x1b : x2b)) + jb + c * 4;
            gload16(src, &auxbuf[bi][0]);
        }
    };

    u64 bv = bitp[0];
    stage(0, 0);
    __syncthreads();
    int cur = 0;

    for (int ph = 0; ph < PHN; ++ph) {
        u64 bvn = 0ull;
        if (ph + 1 < PHN) {
            bvn = bitp[ph + 1];                          // issue before DMA
            stage(cur ^ 1, ph + 1);
        }

        #pragma unroll
        for (int sub = 0; sub < 2; ++sub) {
            const int jl = sub * 32 + g * 8;
            f32x4 d0 = *(const f32x4*)&auxbuf[cur][jl];
            f32x4 d1 = *(const f32x4*)&auxbuf[cur][jl + 4];
            f32x4 x0 = *(const f32x4*)&auxbuf[cur][64 + jl];
            f32x4 x1 = *(const f32x4*)&auxbuf[cur][64 + jl + 4];
            f32x4 y0 = *(const f32x4*)&auxbuf[cur][128 + jl];
            f32x4 y1 = *(const f32x4*)&auxbuf[cur][128 + jl + 4];

            unsigned bsel = (unsigned)((bv >> jl) & 0xFFull);

            float p[8];
            #pragma unroll
            for (int e = 0; e < 4; ++e) {
                float pe0 = (d0[e] >= T) ? C1 * x0[e] : C2 * y0[e];
                p[e]     = (bsel & (1u << e)) ? pe0 : 0.f;
                float pe1 = (d1[e] >= T) ? C1 * x1[e] : C2 * y1[e];
                p[4 + e] = (bsel & (1u << (4 + e))) ? pe1 : 0.f;
            }
            union { s16x8 v; unsigned u[4]; } af;
            af.u[0] = pkbf(p[0], p[1]); af.u[1] = pkbf(p[2], p[3]);
            af.u[2] = pkbf(p[4], p[5]); af.u[3] = pkbf(p[6], p[7]);

            accl = __builtin_amdgcn_mfma_f32_16x16x32_bf16(af.v, ones, accl, 0, 0, 0);
            #pragma unroll
            for (int ot = 0; ot < 8; ++ot) {
                int o = ot * 16 + lr;
                int c = (sub * 4 + g) ^ (o & 7);
                s16x8 Bf = *(const s16x8*)&whbuf[cur][o * 64 + c * 8];
                acc[ot] = __builtin_amdgcn_mfma_f32_16x16x32_bf16(af.v, Bf, acc[ot], 0, 0, 0);
            }
        }
        __syncthreads();
        cur ^= 1;
        bv = bvn;
    }

    const size_t sb = (size_t)blockIdx.y * ((size_t)NROWS * FO_);
    #pragma unroll
    for (int kk = 0; kk < 4; ++kk) {
        int grow = b * N_ + rbase + g * 4 + kk;
        float* pp = pacc + sb + (size_t)grow * FO_ + lr;
        #pragma unroll
        for (int ot = 0; ot < 8; ++ot)
            pp[ot * 16] = acc[ot][kk];
        prow[blockIdx.y * NROWS + grow] = accl[kk];      // same value all lr
    }
}

// ---------------- K4: combine split partials + normalize ----------------
__global__ __launch_bounds__(256) void k4_comb(
    const float* __restrict__ pacc, const float* __restrict__ prow,
    float* __restrict__ out)
{
    const int idx = blockIdx.x * 256 + threadIdx.x;      // 2,097,152
    const int grow = idx >> 7;
    float s = 0.f, rs = 0.f;
    #pragma unroll
    for (int si = 0; si < SPLIT; ++si) {
        s  += pacc[(size_t)si * ((size_t)NROWS * FO_) + idx];
        rs += prow[si * NROWS + grow];
    }
    out[idx] = s / rs;
}

extern "C" void kernel_launch(void* const* d_in, const int* in_sizes, int n_in,
                              void* d_out, int out_size, void* d_ws, size_t ws_size,
                              hipStream_t stream)
{
    const float* h  = (const float*)d_in[0];
    const int* adj  = (const int*)d_in[1];
    const float* Ww = (const float*)d_in[2];
    const float* Wb = (const float*)d_in[3];
    const float* aw = (const float*)d_in[4];
    const float* ab = (const float*)d_in[5];
    float* out = (float*)d_out;

    char* wsb = (char*)d_ws;
    // pacc (32MB, live k3->k4) aliases Wh (8MB, live k1->k2b) — disjoint lifetimes
    float* pacc          = (float*)wsb;
    float* Wh            = (float*)wsb;
    __hip_bfloat16* WhT  = (__hip_bfloat16*)(wsb + 33554432u);   // 4 MB
    u64* bits            = (u64*)(wsb + 37748736u);              // 8 MB
    char* aux            = wsb + 46137344u;
    float* srcv          = (float*)(aux);
    float* dstbv         = (float*)(aux + (64u << 10));
    float* e1v           = (float*)(aux + (128u << 10));
    float* e2v           = (float*)(aux + (192u << 10));
    __hip_bfloat16* whi  = (__hip_bfloat16*)(aux + (256u << 10));
    __hip_bfloat16* wlo  = (__hip_bfloat16*)(aux + (320u << 10));
    float* maxv          = (float*)(aux + (384u << 10));
    float* prow          = (float*)(aux + (448u << 10));         // 256 KB

    k_adjb<<<4096, 256, 0, stream>>>(adj, bits);
    k0_packw<<<128, 256, 0, stream>>>(Ww, whi, wlo);
    k1_wh<<<1024, 256, 0, stream>>>(h, whi, wlo, Wb, Wh);
    k1t<<<256, 256, 0, stream>>>(Wh, WhT);
    k2_vec<<<4096, 256, 0, stream>>>(Wh, aw, ab, srcv, dstbv, e1v, e2v);
    k2b_max<<<4, 256, 0, stream>>>(dstbv, maxv);
    dim3 g3(256, SPLIT);
    k3_gat<<<g3, 256, 0, stream>>>(bits, WhT, srcv, dstbv, e1v, e2v, maxv, pacc, prow);
    k4_comb<<<8192, 256, 0, stream>>>(pacc, prow, out);
}